// Round 4
// baseline (244.919 us; speedup 1.0000x reference)
//
#include <hip/hip_runtime.h>

#define DIM   8192
#define HID   4096
#define PROJ  256
#define NB    32
#define KSP1  16
#define KCH1  (DIM / KSP1)     // 512
#define KT1   (KCH1 / 32)      // 16
#define KSP2  16
#define KCH2  (HID / KSP2)     // 256
#define KT2   (KCH2 / 32)      // 8

typedef __attribute__((ext_vector_type(8))) short bf16x8;
typedef __attribute__((ext_vector_type(4))) float f32x4;

__device__ __forceinline__ float bf2f(unsigned short u) {
    return __uint_as_float(((unsigned)u) << 16);
}
__device__ __forceinline__ unsigned short f2bf(float f) {
    unsigned u = __float_as_uint(f);
    u += 0x7fffu + ((u >> 16) & 1u);           // RNE
    return (unsigned short)(u >> 16);
}
__device__ __forceinline__ unsigned pk2(float a, float b) {
    return (unsigned)f2bf(a) | ((unsigned)f2bf(b) << 16);
}

// bf16-vs-fp32 input dtype probe (see R0/R1 notes). Wave-uniform verdict.
__device__ __forceinline__ bool detect_bf16(const unsigned* __restrict__ xw, int lane) {
    unsigned v = xw[lane];
    int e = (int)((v >> 7) & 0xffu);
    bool pl = (e >= 100 && e <= 135);
    unsigned long long b = __ballot(pl);
    return __popcll(b) >= 32;
}

// async global->LDS, 16B per lane, dest = wave-uniform base + lane*16 (m104)
__device__ __forceinline__ void cp16_g2l(const void* g, void* l) {
    __builtin_amdgcn_global_load_lds(
        (const __attribute__((address_space(1))) void*)g,
        (__attribute__((address_space(3))) void*)l, 16, 0, 0);
}

// ---------------------------------------------------------------------------
// K1: h_part[kc][m][n] = x[m, kc-chunk] @ W1[kc-chunk, n]   (bf16 MFMA)
// grid 1024 = 64 n-blocks x 16 k-chunks; 4 blocks/CU.
// W1 staged via global_load_lds width=16 into unpadded [32][64] tile with
// XOR colblock swizzle (phys_cb = glob_cb ^ (row>>3)) -> B-frag reads are
// max 2-way bank aliased (free, m136). Double-buffered, 1 barrier/iter.
// ---------------------------------------------------------------------------
__global__ __launch_bounds__(256, 4) void gemm1_kernel(
    const void* __restrict__ xv, const void* __restrict__ W1v,
    float* __restrict__ hpart)
{
    __shared__ unsigned short wt[2][2048];       // [buf][32 rows x 64 cols]
    const int t  = threadIdx.x;
    const int nb = blockIdx.x & 63;
    const int kc = blockIdx.x >> 6;
    const int n0 = nb * 64;
    const int k0 = kc * KCH1;

    const bool isbf = detect_bf16((const unsigned*)xv, t & 63);
    const unsigned short* xu  = (const unsigned short*)xv;
    const float*          xf  = (const float*)xv;
    const unsigned short* W1u = (const unsigned short*)W1v;
    const float*          W1f = (const float*)W1v;

    const int lane = t & 63;
    const int w    = t >> 6;       // wave id 0..3
    const int g    = lane >> 4;    // k-group 0..3
    const int ln   = lane & 15;

    // staging geometry: wave w covers tile rows 8w..8w+7; lane l -> row
    // 8w + (l>>3), physical colblock l&7, sourced from global colblock (l&7)^w
    const int srow = w * 8 + (lane >> 3);
    const int scb  = (lane & 7) ^ w;
    const long sgo = (long)srow * HID + n0 + scb * 8;   // + k-offset later
    unsigned short* sl = &wt[0][w * 512];               // + buf*2048 later

    auto issue_stage = [&](int buf, int kt) {
        const unsigned short* gp = W1u + ((long)(k0 + kt * 32) * HID + sgo);
        if (isbf) {
            cp16_g2l((const void*)gp, (void*)(sl + buf * 2048));
        } else {
            const float* gpf = W1f + ((long)(k0 + kt * 32) * HID + sgo);
            float4 f0 = *(const float4*)gpf;
            float4 f1 = *(const float4*)(gpf + 4);
            unsigned* dst = (unsigned*)&wt[buf][srow * 64 + (lane & 7) * 8];
            dst[0] = pk2(f0.x, f0.y); dst[1] = pk2(f0.z, f0.w);
            dst[2] = pk2(f1.x, f1.y); dst[3] = pk2(f1.z, f1.w);
        }
    };
    auto loadA = [&](int kt, int mt) -> bf16x8 {
        const int base = (mt * 16 + ln) * DIM + k0 + kt * 32 + g * 8;
        if (isbf) return *(const bf16x8*)(xu + base);
        float4 f0 = *(const float4*)(xf + base);
        float4 f1 = *(const float4*)(xf + base + 4);
        union { uint4 u; bf16x8 v; } c;
        c.u = make_uint4(pk2(f0.x, f0.y), pk2(f0.z, f0.w),
                         pk2(f1.x, f1.y), pk2(f1.z, f1.w));
        return c.v;
    };

    issue_stage(0, 0);
    bf16x8 areg[2][2];
    areg[0][0] = loadA(0, 0); areg[0][1] = loadA(0, 1);
    areg[1][0] = loadA(1, 0); areg[1][1] = loadA(1, 1);
    __syncthreads();

    f32x4 acc0 = {0.f, 0.f, 0.f, 0.f};
    f32x4 acc1 = {0.f, 0.f, 0.f, 0.f};
    const int bco = w * 16 + ln;
    // B-frag base: row k = g*8+j, col bco; phys cb = (bco>>3)^g
    const int bidx = g * 8 * 64 + (((bco >> 3) ^ g) * 8 + (bco & 7));

    #pragma unroll
    for (int kt = 0; kt < KT1; ++kt) {
        const int cur = kt & 1;
        if (kt + 1 < KT1) issue_stage(cur ^ 1, kt + 1);

        bf16x8 b;
        const unsigned short* wpb = &wt[cur][bidx];
        #pragma unroll
        for (int j = 0; j < 8; ++j) b[j] = (short)wpb[j * 64];

        acc0 = __builtin_amdgcn_mfma_f32_16x16x32_bf16(areg[cur][0], b, acc0, 0, 0, 0);
        acc1 = __builtin_amdgcn_mfma_f32_16x16x32_bf16(areg[cur][1], b, acc1, 0, 0, 0);

        if (kt + 2 < KT1) { areg[cur][0] = loadA(kt + 2, 0); areg[cur][1] = loadA(kt + 2, 1); }
        __syncthreads();
    }

    // C/D layout: row = g*4 + r, col = ln  (m89-verified)
    const int col = n0 + bco;
    #pragma unroll
    for (int r = 0; r < 4; ++r) {
        hpart[(kc * NB + g * 4 + r) * HID + col]      = acc0[r];
        hpart[(kc * NB + 16 + g * 4 + r) * HID + col] = acc1[r];
    }
}

// ---------------------------------------------------------------------------
// K2: reduce k-split partials + BatchNorm(train) + ReLU -> hrelu (bf16).
// b1 provably cancels -> skipped. grid 64 blocks x 256 thr; block = 64 cols;
// thread (c4 = t&15 -> 4 cols, q = t>>4 -> rows 2q, 2q+1), float4 loads.
// ---------------------------------------------------------------------------
__global__ __launch_bounds__(256) void bnrelu_kernel(
    const float* __restrict__ hpart, const void* __restrict__ gv,
    const void* __restrict__ bev, unsigned short* __restrict__ hrelu,
    const void* __restrict__ xv)
{
    __shared__ float red[16][64];
    __shared__ float ssc[64], sbe[64], smu[64];
    const int t  = threadIdx.x;
    const int c4 = t & 15, q = t >> 4;
    const int n0 = blockIdx.x * 64;
    const int nb = n0 + c4 * 4;
    const bool isbf = detect_bf16((const unsigned*)xv, t & 63);

    f32x4 h0 = {0.f, 0.f, 0.f, 0.f};
    f32x4 h1 = {0.f, 0.f, 0.f, 0.f};
    #pragma unroll
    for (int kc = 0; kc < KSP1; ++kc) {
        h0 += *(const f32x4*)(hpart + (size_t)(kc * 32 + 2 * q) * HID + nb);
        h1 += *(const f32x4*)(hpart + (size_t)(kc * 32 + 2 * q + 1) * HID + nb);
    }
    *(f32x4*)&red[q][c4 * 4] = h0 + h1;
    __syncthreads();
    if (t < 64) {
        float s = 0.f;
        #pragma unroll
        for (int i = 0; i < 16; ++i) s += red[i][t];
        smu[t] = s * (1.f / 32.f);
    }
    __syncthreads();
    const f32x4 mu = *(const f32x4*)&smu[c4 * 4];
    const f32x4 d0 = h0 - mu, d1 = h1 - mu;
    *(f32x4*)&red[q][c4 * 4] = d0 * d0 + d1 * d1;
    __syncthreads();
    if (t < 64) {
        float v = 0.f;
        #pragma unroll
        for (int i = 0; i < 16; ++i) v += red[i][t];
        v *= (1.f / 32.f);
        const int nn = n0 + t;
        const float ga = isbf ? bf2f(((const unsigned short*)gv)[nn])  : ((const float*)gv)[nn];
        const float be = isbf ? bf2f(((const unsigned short*)bev)[nn]) : ((const float*)bev)[nn];
        ssc[t] = ga * rsqrtf(v + 1e-5f);
        sbe[t] = be;
    }
    __syncthreads();
    const f32x4 sc = *(const f32x4*)&ssc[c4 * 4];
    const f32x4 be = *(const f32x4*)&sbe[c4 * 4];
    f32x4 r0 = d0 * sc + be;
    f32x4 r1 = d1 * sc + be;
    ushort4 o0, o1;
    o0.x = f2bf(fmaxf(r0.x, 0.f)); o0.y = f2bf(fmaxf(r0.y, 0.f));
    o0.z = f2bf(fmaxf(r0.z, 0.f)); o0.w = f2bf(fmaxf(r0.w, 0.f));
    o1.x = f2bf(fmaxf(r1.x, 0.f)); o1.y = f2bf(fmaxf(r1.y, 0.f));
    o1.z = f2bf(fmaxf(r1.z, 0.f)); o1.w = f2bf(fmaxf(r1.w, 0.f));
    *(ushort4*)(hrelu + (size_t)(2 * q) * HID + nb)     = o0;
    *(ushort4*)(hrelu + (size_t)(2 * q + 1) * HID + nb) = o1;
}

// ---------------------------------------------------------------------------
// K3: ppart[kc][m][p] = hrelu[m, kc-chunk] @ W2[kc-chunk, p]  (bf16 MFMA)
// grid 64 = 4 n-blocks x 16 k-chunks; staged-tile structure (R3, verified).
// ---------------------------------------------------------------------------
__global__ __launch_bounds__(256, 4) void gemm2_kernel(
    const unsigned short* __restrict__ hrelu, const void* __restrict__ W2v,
    float* __restrict__ ppart, const void* __restrict__ xv)
{
    __shared__ unsigned short wt[2 * 32 * 66];
    const int t  = threadIdx.x;
    const int nb = blockIdx.x & 3;
    const int kc = blockIdx.x >> 2;
    const int n0 = nb * 64;
    const int k0 = kc * KCH2;

    const bool isbf = detect_bf16((const unsigned*)xv, t & 63);
    const unsigned short* W2u = (const unsigned short*)W2v;
    const float*          W2f = (const float*)W2v;

    const int lane = t & 63;
    const int w    = t >> 6;
    const int g    = lane >> 4;
    const int ln   = lane & 15;
    const int wr   = t >> 3;
    const int wc   = (t & 7) * 8;

    auto loadW2 = [&](int kt) -> uint4 {
        const int base = (k0 + kt * 32 + wr) * PROJ + n0 + wc;
        if (isbf) return *(const uint4*)(W2u + base);
        float4 f0 = *(const float4*)(W2f + base);
        float4 f1 = *(const float4*)(W2f + base + 4);
        return make_uint4(pk2(f0.x, f0.y), pk2(f0.z, f0.w),
                          pk2(f1.x, f1.y), pk2(f1.z, f1.w));
    };
    auto storeTile = [&](int buf, uint4 v) {
        unsigned* dst = (unsigned*)&wt[buf * 2112 + wr * 66 + wc];
        dst[0] = v.x; dst[1] = v.y; dst[2] = v.z; dst[3] = v.w;
    };
    auto loadA = [&](int kt, int mt) -> bf16x8 {
        return *(const bf16x8*)(hrelu + (mt * 16 + ln) * HID + k0 + kt * 32 + g * 8);
    };

    storeTile(0, loadW2(0));
    uint4 pf[3];
    pf[0] = loadW2(1); pf[1] = loadW2(2); pf[2] = loadW2(3);
    bf16x8 areg[2][2];
    areg[0][0] = loadA(0, 0); areg[0][1] = loadA(0, 1);
    areg[1][0] = loadA(1, 0); areg[1][1] = loadA(1, 1);
    __syncthreads();

    f32x4 acc0 = {0.f, 0.f, 0.f, 0.f};
    f32x4 acc1 = {0.f, 0.f, 0.f, 0.f};
    const int bco = w * 16 + ln;

    #pragma unroll
    for (int kt = 0; kt < KT2; ++kt) {
        const int cur = kt & 1;
        bf16x8 b;
        const unsigned short* wpb = &wt[cur * 2112 + g * 528 + bco];
        #pragma unroll
        for (int j = 0; j < 8; ++j) b[j] = (short)wpb[j * 66];

        acc0 = __builtin_amdgcn_mfma_f32_16x16x32_bf16(areg[cur][0], b, acc0, 0, 0, 0);
        acc1 = __builtin_amdgcn_mfma_f32_16x16x32_bf16(areg[cur][1], b, acc1, 0, 0, 0);

        if (kt + 2 < KT2) { areg[cur][0] = loadA(kt + 2, 0); areg[cur][1] = loadA(kt + 2, 1); }
        if (kt + 1 < KT2) storeTile(cur ^ 1, pf[kt % 3]);
        if (kt + 4 < KT2) pf[kt % 3] = loadW2(kt + 4);
        __syncthreads();
    }

    const int col = n0 + bco;
    #pragma unroll
    for (int r = 0; r < 4; ++r) {
        ppart[(kc * NB + g * 4 + r) * PROJ + col]      = acc0[r];
        ppart[(kc * NB + 16 + g * 4 + r) * PROJ + col] = acc1[r];
    }
}

// ---------------------------------------------------------------------------
// K4: fold k-split reduce of ppart (+b2), L2-normalize, symmetric loss,
// hedged scalar write. Single block, 1024 threads. sims symmetric -> t1==t2.
// ---------------------------------------------------------------------------
__global__ __launch_bounds__(1024) void loss_kernel(
    const float* __restrict__ ppart, const void* __restrict__ b2v,
    const void* __restrict__ xv, unsigned* __restrict__ out)
{
    __shared__ float ps[32][260];
    __shared__ float npart2[32][8];
    __shared__ float inrm[32];
    __shared__ float rowtot[32];
    const int t = threadIdx.x;
    const bool isbf = detect_bf16((const unsigned*)xv, t & 63);

    #pragma unroll
    for (int i = 0; i < 8; ++i) {
        const int o = i * 1024 + t;          // 0..8191
        float s = 0.f;
        #pragma unroll
        for (int s16 = 0; s16 < KSP2; ++s16) s += ppart[s16 * (NB * PROJ) + o];
        const int c = o & 255;
        s += isbf ? bf2f(((const unsigned short*)b2v)[c]) : ((const float*)b2v)[c];
        ps[o >> 8][c] = s;
    }
    __syncthreads();

    if (t < 256) {
        const int r = t >> 3, seg = t & 7;
        float s = 0.f;
        #pragma unroll
        for (int c = 0; c < 32; ++c) { float v = ps[r][seg * 32 + c]; s += v * v; }
        npart2[r][seg] = s;
    }
    __syncthreads();
    if (t < 32) {
        float s = 0.f;
        #pragma unroll
        for (int j = 0; j < 8; ++j) s += npart2[t][j];
        inrm[t] = rsqrtf(s);
    }
    __syncthreads();

    const int wv   = t >> 6;
    const int lane = t & 63;
    const int j    = (lane >> 1) & 31;
    const int half = lane & 1;
    #pragma unroll
    for (int rr = 0; rr < 2; ++rr) {
        const int i = wv * 2 + rr;
        float acc = 0.f;
        const int cb = half * 128;
        #pragma unroll
        for (int c = 0; c < 128; c += 4) {
            float4 a = *(const float4*)&ps[i][cb + c];
            float4 b = *(const float4*)&ps[j][cb + c];
            acc += a.x * b.x + a.y * b.y + a.z * b.z + a.w * b.w;
        }
        acc += __shfl_xor(acc, 1);

        const float sim = acc * inrm[i] * inrm[j] * 10.0f;   // 1/TEMP
        const float E   = __expf(sim);
        const bool pos  = ((j & 7) == (i & 7));              // includes j == i

        float nv = (!pos && half == 0) ? E : 0.f;
        #pragma unroll
        for (int s = 1; s < 64; s <<= 1) nv += __shfl_xor(nv, s);
        float pv = (pos && half == 0) ? (logf(E + nv) - sim) : 0.f;
        #pragma unroll
        for (int s = 1; s < 64; s <<= 1) pv += __shfl_xor(pv, s);
        if (lane == 0) rowtot[i] = pv;
    }
    __syncthreads();

    if (t < 64) {
        float v = (t < 32) ? rowtot[t] : 0.f;
        #pragma unroll
        for (int s = 1; s < 64; s <<= 1) v += __shfl_xor(v, s);
        if (t == 0) {
            const float loss = v * (1.0f / 128.0f);
            // dtype-hedged scalar: low16 = RNE bf16(loss); full word ~ fp32(loss)
            const unsigned lb = (unsigned)f2bf(loss);
            const unsigned base = (__float_as_uint(loss) & 0xffff0000u) | lb;
            unsigned best = base;
            float ebest = fabsf(__uint_as_float(base) - loss);
            const unsigned cp = base + 0x10000u;
            const float ep = fabsf(__uint_as_float(cp) - loss);
            if (ep < ebest) { best = cp; ebest = ep; }
            const unsigned cm = base - 0x10000u;
            const float em = fabsf(__uint_as_float(cm) - loss);
            if (em < ebest) { best = cm; }
            out[0] = best;
        }
    }
}

extern "C" void kernel_launch(void* const* d_in, const int* in_sizes, int n_in,
                              void* d_out, int out_size, void* d_ws, size_t ws_size,
                              hipStream_t stream) {
    const void* x  = d_in[0];
    const void* W1 = d_in[1];
    // d_in[2] = b1: provably cancels in BatchNorm -> unused
    const void* ga = d_in[3];
    const void* be = d_in[4];
    const void* W2 = d_in[5];
    const void* b2 = d_in[6];

    char* wsp = (char*)d_ws;
    float* hpart = (float*)wsp;                 wsp += (size_t)KSP1 * NB * HID * 4;  // 8 MB
    unsigned short* hrelu = (unsigned short*)wsp; wsp += (size_t)NB * HID * 2;       // 256 KB
    float* ppart = (float*)wsp;                 wsp += (size_t)KSP2 * NB * PROJ * 4; // 512 KB

    gemm1_kernel<<<1024, 256, 0, stream>>>(x, W1, hpart);
    bnrelu_kernel<<<64, 256, 0, stream>>>(hpart, ga, be, hrelu, x);
    gemm2_kernel<<<64, 256, 0, stream>>>(hrelu, W2, ppart, x);
    loss_kernel<<<1, 1024, 0, stream>>>(ppart, b2, x, (unsigned*)d_out);
}

// Round 5
// 242.231 us; speedup vs baseline: 1.0111x; 1.0111x over previous
//
#include <hip/hip_runtime.h>

#define DIM   8192
#define HID   4096
#define PROJ  256
#define NB    32
#define KSP1  16
#define KCH1  (DIM / KSP1)     // 512
#define KT1   (KCH1 / 32)      // 16
#define KSP2  16
#define KCH2  (HID / KSP2)     // 256
#define KT2   (KCH2 / 32)      // 8

typedef __attribute__((ext_vector_type(8))) short bf16x8;
typedef __attribute__((ext_vector_type(4))) float f32x4;

__device__ __forceinline__ float bf2f(unsigned short u) {
    return __uint_as_float(((unsigned)u) << 16);
}
__device__ __forceinline__ unsigned short f2bf(float f) {
    unsigned u = __float_as_uint(f);
    u += 0x7fffu + ((u >> 16) & 1u);           // RNE
    return (unsigned short)(u >> 16);
}
__device__ __forceinline__ unsigned pk2(float a, float b) {
    return (unsigned)f2bf(a) | ((unsigned)f2bf(b) << 16);
}

// bf16-vs-fp32 input dtype probe (see R0/R1 notes). Wave-uniform verdict.
__device__ __forceinline__ bool detect_bf16(const unsigned* __restrict__ xw, int lane) {
    unsigned v = xw[lane];
    int e = (int)((v >> 7) & 0xffu);
    bool pl = (e >= 100 && e <= 135);
    unsigned long long b = __ballot(pl);
    return __popcll(b) >= 32;
}

// ---------------------------------------------------------------------------
// K1: h_part[kc][m][n] = x[m, kc-chunk] @ W1[kc-chunk, n]   (bf16 MFMA)
// BARRIER-FREE: no LDS, no __syncthreads in the K-loop. Each wave owns a
// 16-col strip; B-fragments gathered directly from global W1 (8 u16 loads,
// 4-rows x 32B segments; 4 waves/block cover full 128B lines -> no overfetch).
// 4-tile register pipeline; waves fully independent -> no vmcnt(0) drain.
// grid 1024 = 64 n-blocks x 16 k-chunks; 4 blocks/CU, 16 waves/CU.
// ---------------------------------------------------------------------------
__global__ __launch_bounds__(256, 4) void gemm1_kernel(
    const void* __restrict__ xv, const void* __restrict__ W1v,
    float* __restrict__ hpart)
{
    const int t  = threadIdx.x;
    const int nb = blockIdx.x & 63;
    const int kc = blockIdx.x >> 6;
    const int k0 = kc * KCH1;

    const bool isbf = detect_bf16((const unsigned*)xv, t & 63);
    const unsigned short* xu  = (const unsigned short*)xv;
    const float*          xf  = (const float*)xv;
    const unsigned short* W1u = (const unsigned short*)W1v;
    const float*          W1f = (const float*)W1v;

    const int lane  = t & 63;
    const int w     = t >> 6;       // wave id 0..3 -> 16-col strip
    const int g     = lane >> 4;    // k-group 0..3
    const int ln    = lane & 15;
    const int nbase = nb * 64 + w * 16;

    // B fragment: B[k = g*8+j][n = nbase+ln], straight from global
    auto loadB = [&](int kt) -> bf16x8 {
        bf16x8 b;
        const long rb = (long)(k0 + kt * 32 + g * 8) * HID + nbase + ln;
        if (isbf) {
            #pragma unroll
            for (int j = 0; j < 8; ++j) b[j] = (short)W1u[rb + (long)j * HID];
        } else {
            #pragma unroll
            for (int j = 0; j < 8; ++j) b[j] = (short)f2bf(W1f[rb + (long)j * HID]);
        }
        return b;
    };
    // A fragment: x[m = mt*16+ln][k = g*8 + j]  (m120-verified layout)
    auto loadA = [&](int kt, int mt) -> bf16x8 {
        const int base = (mt * 16 + ln) * DIM + k0 + kt * 32 + g * 8;
        if (isbf) return *(const bf16x8*)(xu + base);
        float4 f0 = *(const float4*)(xf + base);
        float4 f1 = *(const float4*)(xf + base + 4);
        union { uint4 u; bf16x8 v; } c;
        c.u = make_uint4(pk2(f0.x, f0.y), pk2(f0.z, f0.w),
                         pk2(f1.x, f1.y), pk2(f1.z, f1.w));
        return c.v;
    };

    bf16x8 bb[4], a0[4], a1[4];
    #pragma unroll
    for (int i = 0; i < 4; ++i) {
        bb[i] = loadB(i); a0[i] = loadA(i, 0); a1[i] = loadA(i, 1);
    }

    f32x4 acc0 = {0.f, 0.f, 0.f, 0.f};
    f32x4 acc1 = {0.f, 0.f, 0.f, 0.f};

    #pragma unroll
    for (int kt = 0; kt < KT1; ++kt) {
        const int s = kt & 3;
        acc0 = __builtin_amdgcn_mfma_f32_16x16x32_bf16(a0[s], bb[s], acc0, 0, 0, 0);
        acc1 = __builtin_amdgcn_mfma_f32_16x16x32_bf16(a1[s], bb[s], acc1, 0, 0, 0);
        if (kt + 4 < KT1) {
            bb[s] = loadB(kt + 4);
            a0[s] = loadA(kt + 4, 0);
            a1[s] = loadA(kt + 4, 1);
        }
    }

    // C/D layout: row = g*4 + r, col = ln  (m89-verified)
    const int col = nbase + ln;
    #pragma unroll
    for (int r = 0; r < 4; ++r) {
        hpart[(kc * NB + g * 4 + r) * HID + col]      = acc0[r];
        hpart[(kc * NB + 16 + g * 4 + r) * HID + col] = acc1[r];
    }
}

// ---------------------------------------------------------------------------
// K2: reduce k-split partials + BatchNorm(train) + ReLU -> hrelu (bf16).
// b1 provably cancels -> skipped. grid 64 blocks x 256 thr; float4 loads.
// ---------------------------------------------------------------------------
__global__ __launch_bounds__(256) void bnrelu_kernel(
    const float* __restrict__ hpart, const void* __restrict__ gv,
    const void* __restrict__ bev, unsigned short* __restrict__ hrelu,
    const void* __restrict__ xv)
{
    __shared__ float red[16][64];
    __shared__ float ssc[64], sbe[64], smu[64];
    const int t  = threadIdx.x;
    const int c4 = t & 15, q = t >> 4;
    const int n0 = blockIdx.x * 64;
    const int nb = n0 + c4 * 4;
    const bool isbf = detect_bf16((const unsigned*)xv, t & 63);

    f32x4 h0 = {0.f, 0.f, 0.f, 0.f};
    f32x4 h1 = {0.f, 0.f, 0.f, 0.f};
    #pragma unroll
    for (int kc = 0; kc < KSP1; ++kc) {
        h0 += *(const f32x4*)(hpart + (size_t)(kc * 32 + 2 * q) * HID + nb);
        h1 += *(const f32x4*)(hpart + (size_t)(kc * 32 + 2 * q + 1) * HID + nb);
    }
    *(f32x4*)&red[q][c4 * 4] = h0 + h1;
    __syncthreads();
    if (t < 64) {
        float s = 0.f;
        #pragma unroll
        for (int i = 0; i < 16; ++i) s += red[i][t];
        smu[t] = s * (1.f / 32.f);
    }
    __syncthreads();
    const f32x4 mu = *(const f32x4*)&smu[c4 * 4];
    const f32x4 d0 = h0 - mu, d1 = h1 - mu;
    *(f32x4*)&red[q][c4 * 4] = d0 * d0 + d1 * d1;
    __syncthreads();
    if (t < 64) {
        float v = 0.f;
        #pragma unroll
        for (int i = 0; i < 16; ++i) v += red[i][t];
        v *= (1.f / 32.f);
        const int nn = n0 + t;
        const float ga = isbf ? bf2f(((const unsigned short*)gv)[nn])  : ((const float*)gv)[nn];
        const float be = isbf ? bf2f(((const unsigned short*)bev)[nn]) : ((const float*)bev)[nn];
        ssc[t] = ga * rsqrtf(v + 1e-5f);
        sbe[t] = be;
    }
    __syncthreads();
    const f32x4 sc = *(const f32x4*)&ssc[c4 * 4];
    const f32x4 be = *(const f32x4*)&sbe[c4 * 4];
    f32x4 r0 = d0 * sc + be;
    f32x4 r1 = d1 * sc + be;
    ushort4 o0, o1;
    o0.x = f2bf(fmaxf(r0.x, 0.f)); o0.y = f2bf(fmaxf(r0.y, 0.f));
    o0.z = f2bf(fmaxf(r0.z, 0.f)); o0.w = f2bf(fmaxf(r0.w, 0.f));
    o1.x = f2bf(fmaxf(r1.x, 0.f)); o1.y = f2bf(fmaxf(r1.y, 0.f));
    o1.z = f2bf(fmaxf(r1.z, 0.f)); o1.w = f2bf(fmaxf(r1.w, 0.f));
    *(ushort4*)(hrelu + (size_t)(2 * q) * HID + nb)     = o0;
    *(ushort4*)(hrelu + (size_t)(2 * q + 1) * HID + nb) = o1;
}

// ---------------------------------------------------------------------------
// K3: ppart[kc][m][p] = hrelu[m, kc-chunk] @ W2[kc-chunk, p]  (bf16 MFMA)
// Same barrier-free direct-gather structure as K1. grid 64 = 4 x 16.
// ---------------------------------------------------------------------------
__global__ __launch_bounds__(256, 4) void gemm2_kernel(
    const unsigned short* __restrict__ hrelu, const void* __restrict__ W2v,
    float* __restrict__ ppart, const void* __restrict__ xv)
{
    const int t  = threadIdx.x;
    const int nb = blockIdx.x & 3;
    const int kc = blockIdx.x >> 2;
    const int k0 = kc * KCH2;

    const bool isbf = detect_bf16((const unsigned*)xv, t & 63);
    const unsigned short* W2u = (const unsigned short*)W2v;
    const float*          W2f = (const float*)W2v;

    const int lane  = t & 63;
    const int w     = t >> 6;
    const int g     = lane >> 4;
    const int ln    = lane & 15;
    const int nbase = nb * 64 + w * 16;

    auto loadB = [&](int kt) -> bf16x8 {
        bf16x8 b;
        const long rb = (long)(k0 + kt * 32 + g * 8) * PROJ + nbase + ln;
        if (isbf) {
            #pragma unroll
            for (int j = 0; j < 8; ++j) b[j] = (short)W2u[rb + (long)j * PROJ];
        } else {
            #pragma unroll
            for (int j = 0; j < 8; ++j) b[j] = (short)f2bf(W2f[rb + (long)j * PROJ]);
        }
        return b;
    };
    auto loadA = [&](int kt, int mt) -> bf16x8 {
        return *(const bf16x8*)(hrelu + (mt * 16 + ln) * HID + k0 + kt * 32 + g * 8);
    };

    bf16x8 bb[4], a0[4], a1[4];
    #pragma unroll
    for (int i = 0; i < 4; ++i) {
        bb[i] = loadB(i); a0[i] = loadA(i, 0); a1[i] = loadA(i, 1);
    }

    f32x4 acc0 = {0.f, 0.f, 0.f, 0.f};
    f32x4 acc1 = {0.f, 0.f, 0.f, 0.f};

    #pragma unroll
    for (int kt = 0; kt < KT2; ++kt) {
        const int s = kt & 3;
        acc0 = __builtin_amdgcn_mfma_f32_16x16x32_bf16(a0[s], bb[s], acc0, 0, 0, 0);
        acc1 = __builtin_amdgcn_mfma_f32_16x16x32_bf16(a1[s], bb[s], acc1, 0, 0, 0);
        if (kt + 4 < KT2) {
            bb[s] = loadB(kt + 4);
            a0[s] = loadA(kt + 4, 0);
            a1[s] = loadA(kt + 4, 1);
        }
    }

    const int col = nbase + ln;
    #pragma unroll
    for (int r = 0; r < 4; ++r) {
        ppart[(kc * NB + g * 4 + r) * PROJ + col]      = acc0[r];
        ppart[(kc * NB + 16 + g * 4 + r) * PROJ + col] = acc1[r];
    }
}

// ---------------------------------------------------------------------------
// K4: fold k-split reduce of ppart (+b2), L2-normalize, symmetric loss,
// hedged scalar write. Single block, 1024 threads. sims symmetric -> t1==t2.
// ---------------------------------------------------------------------------
__global__ __launch_bounds__(1024) void loss_kernel(
    const float* __restrict__ ppart, const void* __restrict__ b2v,
    const void* __restrict__ xv, unsigned* __restrict__ out)
{
    __shared__ float ps[32][260];
    __shared__ float npart2[32][8];
    __shared__ float inrm[32];
    __shared__ float rowtot[32];
    const int t = threadIdx.x;
    const bool isbf = detect_bf16((const unsigned*)xv, t & 63);

    #pragma unroll
    for (int i = 0; i < 8; ++i) {
        const int o = i * 1024 + t;          // 0..8191
        float s = 0.f;
        #pragma unroll
        for (int s16 = 0; s16 < KSP2; ++s16) s += ppart[s16 * (NB * PROJ) + o];
        const int c = o & 255;
        s += isbf ? bf2f(((const unsigned short*)b2v)[c]) : ((const float*)b2v)[c];
        ps[o >> 8][c] = s;
    }
    __syncthreads();

    if (t < 256) {
        const int r = t >> 3, seg = t & 7;
        float s = 0.f;
        #pragma unroll
        for (int c = 0; c < 32; ++c) { float v = ps[r][seg * 32 + c]; s += v * v; }
        npart2[r][seg] = s;
    }
    __syncthreads();
    if (t < 32) {
        float s = 0.f;
        #pragma unroll
        for (int j = 0; j < 8; ++j) s += npart2[t][j];
        inrm[t] = rsqrtf(s);
    }
    __syncthreads();

    const int wv   = t >> 6;
    const int lane = t & 63;
    const int j    = (lane >> 1) & 31;
    const int half = lane & 1;
    #pragma unroll
    for (int rr = 0; rr < 2; ++rr) {
        const int i = wv * 2 + rr;
        float acc = 0.f;
        const int cb = half * 128;
        #pragma unroll
        for (int c = 0; c < 128; c += 4) {
            float4 a = *(const float4*)&ps[i][cb + c];
            float4 b = *(const float4*)&ps[j][cb + c];
            acc += a.x * b.x + a.y * b.y + a.z * b.z + a.w * b.w;
        }
        acc += __shfl_xor(acc, 1);

        const float sim = acc * inrm[i] * inrm[j] * 10.0f;   // 1/TEMP
        const float E   = __expf(sim);
        const bool pos  = ((j & 7) == (i & 7));              // includes j == i

        float nv = (!pos && half == 0) ? E : 0.f;
        #pragma unroll
        for (int s = 1; s < 64; s <<= 1) nv += __shfl_xor(nv, s);
        float pv = (pos && half == 0) ? (logf(E + nv) - sim) : 0.f;
        #pragma unroll
        for (int s = 1; s < 64; s <<= 1) pv += __shfl_xor(pv, s);
        if (lane == 0) rowtot[i] = pv;
    }
    __syncthreads();

    if (t < 64) {
        float v = (t < 32) ? rowtot[t] : 0.f;
        #pragma unroll
        for (int s = 1; s < 64; s <<= 1) v += __shfl_xor(v, s);
        if (t == 0) {
            const float loss = v * (1.0f / 128.0f);
            // dtype-hedged scalar: low16 = RNE bf16(loss); full word ~ fp32(loss)
            const unsigned lb = (unsigned)f2bf(loss);
            const unsigned base = (__float_as_uint(loss) & 0xffff0000u) | lb;
            unsigned best = base;
            float ebest = fabsf(__uint_as_float(base) - loss);
            const unsigned cp = base + 0x10000u;
            const float ep = fabsf(__uint_as_float(cp) - loss);
            if (ep < ebest) { best = cp; ebest = ep; }
            const unsigned cm = base - 0x10000u;
            const float em = fabsf(__uint_as_float(cm) - loss);
            if (em < ebest) { best = cm; }
            out[0] = best;
        }
    }
}

extern "C" void kernel_launch(void* const* d_in, const int* in_sizes, int n_in,
                              void* d_out, int out_size, void* d_ws, size_t ws_size,
                              hipStream_t stream) {
    const void* x  = d_in[0];
    const void* W1 = d_in[1];
    // d_in[2] = b1: provably cancels in BatchNorm -> unused
    const void* ga = d_in[3];
    const void* be = d_in[4];
    const void* W2 = d_in[5];
    const void* b2 = d_in[6];

    char* wsp = (char*)d_ws;
    float* hpart = (float*)wsp;                 wsp += (size_t)KSP1 * NB * HID * 4;  // 8 MB
    unsigned short* hrelu = (unsigned short*)wsp; wsp += (size_t)NB * HID * 2;       // 256 KB
    float* ppart = (float*)wsp;                 wsp += (size_t)KSP2 * NB * PROJ * 4; // 512 KB

    gemm1_kernel<<<1024, 256, 0, stream>>>(x, W1, hpart);
    bnrelu_kernel<<<64, 256, 0, stream>>>(hpart, ga, be, hrelu, x);
    gemm2_kernel<<<64, 256, 0, stream>>>(hrelu, W2, ppart, x);
    loss_kernel<<<1, 1024, 0, stream>>>(ppart, b2, x, (unsigned*)d_out);
}